// Round 7
// baseline (19284.950 us; speedup 1.0000x reference)
//
#include <hip/hip_runtime.h>
#include <stdint.h>

#define N_NODES 100000
#define N_EDGES 1600000
#define CH 128
#define EDGE_DIM 16

__device__ __forceinline__ float bf2f(ushort u) {
  union { uint i; float f; } c; c.i = ((uint)u) << 16; return c.f;
}
__device__ __forceinline__ ushort f2bf(float f) {
  union { float f; uint i; } c; c.f = f;
  return (ushort)((c.i + 0x7FFFu + ((c.i >> 16) & 1u)) >> 16);
}
// dtype-dispatched scalar load (f32 or bf16 buffer)
__device__ __forceinline__ float ldf(const void* p, int f32, size_t i) {
  return f32 ? ((const float*)p)[i] : bf2f(((const ushort*)p)[i]);
}
// dtype-dispatched paired load: elements (2*pi, 2*pi+1)
__device__ __forceinline__ float2 ld2(const void* p, int f32, size_t pi) {
  if (f32) return ((const float2*)p)[pi];
  uint u = ((const uint*)p)[pi];
  return make_float2(bf2f((ushort)(u & 0xFFFF)), bf2f((ushort)(u >> 16)));
}
// x_sel: 0 = force bf16, 1 = use detected x flag, 2 = force f32
__device__ __forceinline__ int resolve_f32(int x_sel, const int* flags) {
  return (x_sel == 2) ? 1 : (x_sel == 1 ? flags[1] : 0);
}

// ---------------------------------------------------------------- runtime layout/dtype detection
// flags[0]=1 -> edge_index int32 [2,E] (odd int32 slots of int64 values <1e5 are 0).
// flags[1..3]=1 -> x / edge_attr / weights are f32 (bf16 N(0,1)/xavier data never has
// exponent 0xFF; low halves of random f32 words hit it with p=1/256 per sample).
__global__ __launch_bounds__(256) void detect_kernel(const int* __restrict__ ei,
                                                     const ushort* __restrict__ xu,
                                                     const ushort* __restrict__ eau,
                                                     const ushort* __restrict__ wu,
                                                     int* __restrict__ flags) {
  int any = 0, fx = 0, fe = 0, fw = 0;
  for (int i = threadIdx.x; i < 4096; i += 256) any |= ei[2 * i + 1];
  for (int i = threadIdx.x; i < 16384; i += 256) {
    fx |= (((xu[2 * i] >> 7) & 0xFF) == 0xFF);
    fe |= (((eau[2 * i] >> 7) & 0xFF) == 0xFF);
  }
  for (int i = threadIdx.x; i < 8192; i += 256) {
    fw |= (((wu[2 * i] >> 7) & 0xFF) == 0xFF);
  }
  if (any) atomicOr(flags + 0, 1);
  if (fx)  atomicOr(flags + 1, 1);
  if (fe)  atomicOr(flags + 2, 1);
  if (fw)  atomicOr(flags + 3, 1);
}

__device__ __forceinline__ void load_edge(const int* __restrict__ ei, int i32, int e,
                                          int& s, int& d) {
  if (i32) { s = ei[e]; d = ei[N_EDGES + e]; }
  else     { s = ei[2 * e]; d = ei[2 * N_EDGES + 2 * e]; }
  s = min(max(s, 0), N_NODES - 1);
  d = min(max(d, 0), N_NODES - 1);
}

// ---------------------------------------------------------------- degree count
__global__ __launch_bounds__(256) void count_kernel(const int* __restrict__ ei,
                                                    const int* __restrict__ flags,
                                                    int* __restrict__ cnt) {
  int e = blockIdx.x * 256 + threadIdx.x;
  if (e >= N_EDGES) return;
  int s, d;
  load_edge(ei, flags[0], e, s, d);
  atomicAdd(&cnt[d], 1);
}

// ---------------------------------------------------------------- message: one wave per edge, lane owns 2 out-channels
// msg = relu([x[src] || ea[e]] @ W + b); atomic scatter-add into agg[dst]
__global__ __launch_bounds__(256) void msg_simple(const void* __restrict__ x, int x_sel,
                                                  const void* __restrict__ ea,
                                                  const void* __restrict__ W,
                                                  const void* __restrict__ bmsg,
                                                  const int* __restrict__ ei,
                                                  const int* __restrict__ flags,
                                                  float* __restrict__ agg) {
  int e = (blockIdx.x * 256 + threadIdx.x) >> 6;
  int lane = threadIdx.x & 63;
  if (e >= N_EDGES) return;
  int s, d;
  load_edge(ei, flags[0], e, s, d);
  const int xf = resolve_f32(x_sel, flags), ef = flags[2], wf = flags[3];
  float acc0 = 0.f, acc1 = 0.f;
#pragma unroll 4
  for (int k = 0; k < CH; ++k) {
    float a = ldf(x, xf, (size_t)s * CH + k);
    float2 w = ld2(W, wf, (size_t)k * 64 + lane);
    acc0 += a * w.x;
    acc1 += a * w.y;
  }
#pragma unroll
  for (int k = 0; k < EDGE_DIM; ++k) {
    float a = ldf(ea, ef, (size_t)e * EDGE_DIM + k);
    float2 w = ld2(W, wf, (size_t)(CH + k) * 64 + lane);
    acc0 += a * w.x;
    acc1 += a * w.y;
  }
  float2 b = ld2(bmsg, wf, lane);
  acc0 = fmaxf(acc0 + b.x, 0.f);
  acc1 = fmaxf(acc1 + b.y, 0.f);
  atomicAdd(&agg[(size_t)d * CH + 2 * lane], acc0);
  atomicAdd(&agg[(size_t)d * CH + 2 * lane + 1], acc1);
}

// ---------------------------------------------------------------- update: one wave per node, lane owns 2 out-channels
// raw = [x[n] || agg[n]/max(cnt,1)] @ W + b.  raw may alias agg: the stores depend
// (through the accumulators) on every agg load of that row, rows are wave-exclusive.
__global__ __launch_bounds__(256) void upd_simple(const void* __restrict__ x, int x_sel,
                                                  const float* __restrict__ agg,
                                                  const int* __restrict__ cnt,
                                                  const void* __restrict__ W,
                                                  const void* __restrict__ bupd,
                                                  const int* __restrict__ flags,
                                                  float* __restrict__ raw) {
  int n = (blockIdx.x * 256 + threadIdx.x) >> 6;
  int lane = threadIdx.x & 63;
  if (n >= N_NODES) return;
  const int xf = resolve_f32(x_sel, flags), wf = flags[3];
  int c = cnt[n];
  float inv = 1.f / (float)(c > 1 ? c : 1);
  float acc0 = 0.f, acc1 = 0.f;
#pragma unroll 4
  for (int k = 0; k < CH; ++k) {
    float a = ldf(x, xf, (size_t)n * CH + k);
    float2 w = ld2(W, wf, (size_t)k * 64 + lane);
    acc0 += a * w.x;
    acc1 += a * w.y;
  }
#pragma unroll 4
  for (int k = 0; k < CH; ++k) {
    float a = agg[(size_t)n * CH + k] * inv;
    float2 w = ld2(W, wf, (size_t)(CH + k) * 64 + lane);
    acc0 += a * w.x;
    acc1 += a * w.y;
  }
  float2 b = ld2(bupd, wf, lane);
  raw[(size_t)n * CH + 2 * lane] = acc0 + b.x;
  raw[(size_t)n * CH + 2 * lane + 1] = acc1 + b.y;
}

// ---------------------------------------------------------------- row L2-normalize + bias (+optional ReLU) -> f32
// OUTPUT IS FLOAT32: the reference returns float32 and the float inputs are
// provably f32 on device (R2 bf16-misread NaN), so d_out is read as f32.
__global__ __launch_bounds__(256) void norm_simple(const float* __restrict__ raw,
                                                   const void* __restrict__ bias,
                                                   const int* __restrict__ flags,
                                                   float* __restrict__ out,
                                                   int relu) {
  int row = blockIdx.x * 4 + (threadIdx.x >> 6);
  int lane = threadIdx.x & 63;
  const int wf = flags[3];
  float v0 = raw[(size_t)row * CH + 2 * lane];
  float v1 = raw[(size_t)row * CH + 2 * lane + 1];
  float ss = v0 * v0 + v1 * v1;
#pragma unroll
  for (int o = 32; o; o >>= 1) ss += __shfl_xor(ss, o);
  float inv = 1.0f / fmaxf(sqrtf(ss), 1e-12f);
  float2 b = ld2(bias, wf, lane);
  float o0 = v0 * inv + b.x;
  float o1 = v1 * inv + b.y;
  if (relu) {
    o0 = fmaxf(o0, 0.0f);
    o1 = fmaxf(o1, 0.0f);
  }
  out[(size_t)row * CH + 2 * lane] = o0;
  out[(size_t)row * CH + 2 * lane + 1] = o1;
}

// ---------------------------------------------------------------- host
extern "C" void kernel_launch(void* const* d_in, const int* in_sizes, int n_in,
                              void* d_out, int out_size, void* d_ws, size_t ws_size,
                              hipStream_t stream) {
  const void* x   = d_in[0];
  const int*  ei  = (const int*)d_in[1];
  const void* ea  = d_in[2];
  const void* wm1 = d_in[3];
  const void* bm1 = d_in[4];
  const void* wu1 = d_in[5];
  const void* bu1 = d_in[6];
  const void* bi1 = d_in[7];
  const void* wm2 = d_in[8];
  const void* bm2 = d_in[9];
  const void* wu2 = d_in[10];
  const void* bu2 = d_in[11];
  const void* bi2 = d_in[12];
  float* out = (float*)d_out;

  // Workspace (51.6 MB): flags | cnt | agg (raw aliased).
  // Layer-1 h (f32, 51.2 MB) lives in d_out: norm1 writes it, layer 2 consumes
  // it (x_sel=2, force-f32), norm2 overwrites d_out with the final f32 output
  // (stream-ordered: upd2 finished reading h before norm2 writes).
  char* base = (char*)d_ws;
  size_t off = 0;
  auto alloc = [&](size_t b) { size_t o = off; off += (b + 255) & ~(size_t)255; return o; };
  size_t flags_o = alloc(16);
  size_t cnt_o   = alloc((size_t)N_NODES * 4);
  size_t agg_o   = alloc((size_t)N_NODES * CH * 4);
  size_t zero_end = off;
  (void)ws_size; (void)n_in; (void)in_sizes; (void)out_size;

  int*   flags = (int*)(base + flags_o);
  int*   cntp  = (int*)(base + cnt_o);
  float* aggp  = (float*)(base + agg_o);
  float* rawp  = aggp;   // alias (see upd_simple note)
  float* hp    = out;    // layer-1 output (f32) lives in d_out

  hipMemsetAsync(base, 0, zero_end, stream);
  detect_kernel<<<1, 256, 0, stream>>>(ei, (const ushort*)x, (const ushort*)ea,
                                       (const ushort*)wm1, flags);
  count_kernel<<<(N_EDGES + 255) / 256, 256, 0, stream>>>(ei, flags, cntp);

  const int mgrid = N_EDGES / 4;        // 1 wave/edge, 4 waves/block
  const int ugrid = (N_NODES + 3) / 4;  // 1 wave/node

  // ---- layer 1
  msg_simple<<<mgrid, 256, 0, stream>>>(x, 1, ea, wm1, bm1, ei, flags, aggp);
  upd_simple<<<ugrid, 256, 0, stream>>>(x, 1, aggp, cntp, wu1, bu1, flags, rawp);
  norm_simple<<<N_NODES / 4, 256, 0, stream>>>(rawp, bi1, flags, hp, 1);

  // ---- layer 2 (h is f32 in d_out -> x_sel=2 forces f32)
  hipMemsetAsync(base + agg_o, 0, (size_t)N_NODES * CH * 4, stream);
  msg_simple<<<mgrid, 256, 0, stream>>>(hp, 2, ea, wm2, bm2, ei, flags, aggp);
  upd_simple<<<ugrid, 256, 0, stream>>>(hp, 2, aggp, cntp, wu2, bu2, flags, rawp);
  norm_simple<<<N_NODES / 4, 256, 0, stream>>>(rawp, bi2, flags, out, 0);
}